// Round 10
// baseline (2336.854 us; speedup 1.0000x reference)
//
#include <hip/hip_runtime.h>
#include <hip/hip_bf16.h>

// DecoderRNNsearch on MI355X — round 11. Base: r10 (2284 us, passed).
// Post-mortem r10: swizzle killed bank conflicts (1.26e7 -> 0) but gemm_bt3
// time unchanged -> conflicts weren't the critical path (structural barrier
// stall is). The -130 us came from the gate 4-way split. absmax bit-identical
// across fp32 reorders -> reorders are safe here.
// This round, two per-step latency trims:
//   (1) step_a: attn scores spread over 256 blocks (was 64 = 1/4 chip);
//       fp32 scores to global, softmax recomputed in gate (exact, r6-verified
//       indexing). step_a = 448 blocks (256 scores + 192 gh).
//   (2) gate: ghs staging (tid<384) runs CONCURRENTLY with softmax+compaction
//       (tid>=384) — one barrier instead of two serialized phases.
// Everything else identical to r10 (swizzled GEMMs, 4-way gather, fp32 ctxWc).

using short8 = __attribute__((ext_vector_type(8))) short;
using f32x4  = __attribute__((ext_vector_type(4))) float;

#define FLAG_ACC 1
#define FLAG_BF  2

__device__ __forceinline__ void gld16(const void* g, void* l) {
  __builtin_amdgcn_global_load_lds(
      (const __attribute__((address_space(1))) unsigned int*)g,
      (__attribute__((address_space(3))) unsigned int*)l, 16, 0, 0);
}

// ---------------- conversion / prep kernels ----------------

__global__ __launch_bounds__(256) void split_bf16_kernel(
    const float* __restrict__ x, __hip_bfloat16* __restrict__ hi,
    __hip_bfloat16* __restrict__ lo, int n)
{
  int i = blockIdx.x * blockDim.x + threadIdx.x;
  int stride = gridDim.x * blockDim.x;
  for (; i < n; i += stride) {
    float v = x[i];
    __hip_bfloat16 h = __float2bfloat16(v);
    hi[i] = h;
    lo[i] = __float2bfloat16(v - __bfloat162float(h));
  }
}

// permute rows j' = 3u+g  <-  source row g*1024+u ; split to bf16 hi/lo
__global__ __launch_bounds__(256) void prep_weights(
    const float* __restrict__ Wih, const float* __restrict__ Whh,
    const float* __restrict__ bih, const float* __restrict__ bhh,
    __hip_bfloat16* __restrict__ WcH, __hip_bfloat16* __restrict__ WcL,
    __hip_bfloat16* __restrict__ We,
    __hip_bfloat16* __restrict__ WhH, __hip_bfloat16* __restrict__ WhL,
    float* __restrict__ bihp, float* __restrict__ bhhp)
{
  const int jp = blockIdx.x;           // 0..3071
  const int u = jp / 3, g = jp - 3 * u;
  const int src = g * 1024 + u;
  for (int c = threadIdx.x; c < 2048; c += 256) {
    float v = Wih[(size_t)src * 2560 + 512 + c];
    __hip_bfloat16 h = __float2bfloat16(v);
    WcH[(size_t)jp * 2048 + c] = h;
    WcL[(size_t)jp * 2048 + c] = __float2bfloat16(v - __bfloat162float(h));
  }
  for (int c = threadIdx.x; c < 512; c += 256)
    We[(size_t)jp * 512 + c] = __float2bfloat16(Wih[(size_t)src * 2560 + c]);
  for (int c = threadIdx.x; c < 1024; c += 256) {
    float v = Whh[(size_t)src * 1024 + c];
    __hip_bfloat16 h = __float2bfloat16(v);
    WhH[(size_t)jp * 1024 + c] = h;
    WhL[(size_t)jp * 1024 + c] = __float2bfloat16(v - __bfloat162float(h));
  }
  if (threadIdx.x == 0) { bihp[jp] = bih[src]; bhhp[jp] = bhh[src]; }
}

__global__ __launch_bounds__(256) void emb_gather(
    const int* __restrict__ tgt, const float* __restrict__ table,
    __hip_bfloat16* __restrict__ outb)
{
  const int row = blockIdx.x;          // b*64+t, 0..4095
  const int v = tgt[row];
  for (int c = threadIdx.x; c < 512; c += 256)
    outb[(size_t)row * 512 + c] = __float2bfloat16(table[(size_t)v * 512 + c]);
}

__global__ __launch_bounds__(256) void h0_init(
    const float* __restrict__ h0, float* __restrict__ hf,
    __hip_bfloat16* __restrict__ hhi, __hip_bfloat16* __restrict__ hlo)
{
  const int i = blockIdx.x * 256 + threadIdx.x;   // grid 256 -> 65536
  float v = h0[i];
  hf[i] = v;
  __hip_bfloat16 h = __float2bfloat16(v);
  hhi[i] = h;
  hlo[i] = __float2bfloat16(v - __bfloat162float(h));
}

// ---------------- bf16 GEMM  C[M,N] = A[M,K] @ B[N,K]^T (single pass) -------
// 128x128 tile, 4 waves, BK=32, global_load_lds staging, XOR-swizzled LDS
// (pre-swizzled global source + swizzled ds_read; conflicts measured 0).

__global__ __launch_bounds__(256) void gemm_bt(
    const short* __restrict__ A, const short* __restrict__ B,
    float* __restrict__ Cf, __hip_bfloat16* __restrict__ Cb,
    const float* __restrict__ bias, int M, int N, int K, int flags)
{
  __shared__ __align__(16) short As[128 * 32];
  __shared__ __align__(16) short Bs[128 * 32];
  const int tid = threadIdx.x, lane = tid & 63, w = tid >> 6;
  const int m0 = blockIdx.y * 128, n0 = blockIdx.x * 128;
  const int wm = (w >> 1) * 64, wn = (w & 1) * 64;
  const int srow = lane >> 2;
  const int scol = (((lane & 3) ^ ((lane >> 3) & 3)) * 8);   // pre-swizzled src
  f32x4 zero = {0.f, 0.f, 0.f, 0.f};
  f32x4 acc[4][4];
#pragma unroll
  for (int i = 0; i < 4; ++i)
#pragma unroll
    for (int j = 0; j < 4; ++j) acc[i][j] = zero;

  for (int k0 = 0; k0 < K; k0 += 32) {
    __syncthreads();
#pragma unroll
    for (int s = 0; s < 2; ++s) {
      const int chunk = w * 2 + s;
      const int r = chunk * 16 + srow;
      gld16(A + (size_t)(m0 + r) * K + k0 + scol, As + chunk * 512);
      gld16(B + (size_t)(n0 + r) * K + k0 + scol, Bs + chunk * 512);
    }
    __syncthreads();
    const int fm = lane & 15, fq = lane >> 4;
    const int cbs = (fq ^ ((fm >> 1) & 3)) * 8;              // swizzled read
    short8 af[4], bq[4];
#pragma unroll
    for (int i = 0; i < 4; ++i)
      af[i] = *(const short8*)(As + (wm + i * 16 + fm) * 32 + cbs);
#pragma unroll
    for (int j = 0; j < 4; ++j)
      bq[j] = *(const short8*)(Bs + (wn + j * 16 + fm) * 32 + cbs);
#pragma unroll
    for (int i = 0; i < 4; ++i)
#pragma unroll
      for (int j = 0; j < 4; ++j)
        acc[i][j] = __builtin_amdgcn_mfma_f32_16x16x32_bf16(af[i], bq[j], acc[i][j], 0, 0, 0);
  }

  const int cn = lane & 15, cq = (lane >> 4) * 4;
#pragma unroll
  for (int i = 0; i < 4; ++i)
#pragma unroll
    for (int j = 0; j < 4; ++j)
#pragma unroll
      for (int r = 0; r < 4; ++r) {
        const int m = m0 + wm + i * 16 + cq + r;
        const int n = n0 + wn + j * 16 + cn;
        float v = acc[i][j][r];
        if (flags & FLAG_ACC) v += Cf[(size_t)m * N + n];
        if (bias) v += bias[n];
        if (flags & FLAG_BF) Cb[(size_t)m * N + n] = __float2bfloat16(v);
        else                 Cf[(size_t)m * N + n] = v;
      }
}

// ---------------- fused split-bf16 triple GEMM --------------------------------
// C = AH@BH^T + AL@BH^T + AH@BL^T  (effective-fp32 product), one staging pass.
// Same XOR-swizzled LDS layout as gemm_bt.

__global__ __launch_bounds__(256) void gemm_bt3(
    const short* __restrict__ AH, const short* __restrict__ AL,
    const short* __restrict__ BH, const short* __restrict__ BL,
    float* __restrict__ Cf, int M, int N, int K)
{
  __shared__ __align__(16) short AsH[128 * 32];
  __shared__ __align__(16) short AsL[128 * 32];
  __shared__ __align__(16) short BsH[128 * 32];
  __shared__ __align__(16) short BsL[128 * 32];
  const int tid = threadIdx.x, lane = tid & 63, w = tid >> 6;
  const int m0 = blockIdx.y * 128, n0 = blockIdx.x * 128;
  const int wm = (w >> 1) * 64, wn = (w & 1) * 64;
  const int srow = lane >> 2;
  const int scol = (((lane & 3) ^ ((lane >> 3) & 3)) * 8);   // pre-swizzled src
  f32x4 zero = {0.f, 0.f, 0.f, 0.f};
  f32x4 acc[4][4];
#pragma unroll
  for (int i = 0; i < 4; ++i)
#pragma unroll
    for (int j = 0; j < 4; ++j) acc[i][j] = zero;

  for (int k0 = 0; k0 < K; k0 += 32) {
    __syncthreads();
#pragma unroll
    for (int s = 0; s < 2; ++s) {
      const int chunk = w * 2 + s;
      const int r = chunk * 16 + srow;
      const size_t ao = (size_t)(m0 + r) * K + k0 + scol;
      const size_t bo = (size_t)(n0 + r) * K + k0 + scol;
      gld16(AH + ao, AsH + chunk * 512);
      gld16(AL + ao, AsL + chunk * 512);
      gld16(BH + bo, BsH + chunk * 512);
      gld16(BL + bo, BsL + chunk * 512);
    }
    __syncthreads();
    const int fm = lane & 15, fq = lane >> 4;
    const int cbs = (fq ^ ((fm >> 1) & 3)) * 8;              // swizzled read
    short8 ah[4], al[4], bh[4], bl[4];
#pragma unroll
    for (int i = 0; i < 4; ++i) {
      const int off = (wm + i * 16 + fm) * 32 + cbs;
      ah[i] = *(const short8*)(AsH + off);
      al[i] = *(const short8*)(AsL + off);
    }
#pragma unroll
    for (int j = 0; j < 4; ++j) {
      const int off = (wn + j * 16 + fm) * 32 + cbs;
      bh[j] = *(const short8*)(BsH + off);
      bl[j] = *(const short8*)(BsL + off);
    }
#pragma unroll
    for (int i = 0; i < 4; ++i)
#pragma unroll
      for (int j = 0; j < 4; ++j) {
        acc[i][j] = __builtin_amdgcn_mfma_f32_16x16x32_bf16(ah[i], bh[j], acc[i][j], 0, 0, 0);
        acc[i][j] = __builtin_amdgcn_mfma_f32_16x16x32_bf16(al[i], bh[j], acc[i][j], 0, 0, 0);
        acc[i][j] = __builtin_amdgcn_mfma_f32_16x16x32_bf16(ah[i], bl[j], acc[i][j], 0, 0, 0);
      }
  }

  const int cn = lane & 15, cq = (lane >> 4) * 4;
#pragma unroll
  for (int i = 0; i < 4; ++i)
#pragma unroll
    for (int j = 0; j < 4; ++j)
#pragma unroll
      for (int r = 0; r < 4; ++r) {
        const int m = m0 + wm + i * 16 + cq + r;
        const int n = n0 + wn + j * 16 + cn;
        Cf[(size_t)m * N + n] = acc[i][j][r];
      }
}

// ---------------- per-step kernel A ------------------------------------------
// blocks 0-255: attn scores fp32 (b = blk>>2, lc = blk&3; 16 l x 16 d-chunks,
// 16-lane shfl reduce). blocks 256-447: gh = Whh_slice @ h, 16 rows/block.

__global__ __launch_bounds__(256) void step_a(
    const float* __restrict__ hf, const float* __restrict__ ctxW,
    const int* __restrict__ lens, float* __restrict__ scoresG,
    const short* __restrict__ hhi, const short* __restrict__ hlo,
    const short* __restrict__ WhH, const short* __restrict__ WhL,
    float* __restrict__ ghG)
{
  const int tid = threadIdx.x;
  if (blockIdx.x < 256) {
    __shared__ float hs[1024];
    const int b = blockIdx.x >> 2, lc = blockIdx.x & 3;
    const int len = lens[b];
    ((float4*)hs)[tid] = ((const float4*)(hf + b * 1024))[tid];
    __syncthreads();
    const int l = lc * 16 + (tid >> 4), dq = tid & 15;
    if (l < len) {
      const float4* row = (const float4*)(ctxW + (size_t)(b * 64 + l) * 1024);
      const float4* hh = (const float4*)hs;
      float sx = 0.f, sy = 0.f, sz = 0.f, sw = 0.f;
#pragma unroll
      for (int i = 0; i < 16; ++i) {
        float4 a = row[i * 16 + dq], c = hh[i * 16 + dq];
        sx += a.x * c.x; sy += a.y * c.y; sz += a.z * c.z; sw += a.w * c.w;
      }
      float s = (sx + sy) + (sz + sw);
#pragma unroll
      for (int off = 8; off > 0; off >>= 1) s += __shfl_xor(s, off);
      if (dq == 0) scoresG[b * 64 + l] = s;
    }
  } else {
    // ---- gh = Whh_slice @ h, 16 rows/block (verified r5/r10) ----
    const int j0 = (blockIdx.x - 256) * 16;
    const int lane = tid & 63, w = tid >> 6;
    const int fm = lane & 15, fq = lane >> 4;
    f32x4 acc = {0.f, 0.f, 0.f, 0.f};
    const short* ah = hhi + (w * 16 + fm) * 1024 + fq * 8;   // batches w*16..+15
    const short* al = hlo + (w * 16 + fm) * 1024 + fq * 8;
    const short* bh = WhH + (size_t)(j0 + fm) * 1024 + fq * 8;
    const short* bl = WhL + (size_t)(j0 + fm) * 1024 + fq * 8;
#pragma unroll 4
    for (int k0 = 0; k0 < 1024; k0 += 32) {
      short8 aH = *(const short8*)(ah + k0);
      short8 aL = *(const short8*)(al + k0);
      short8 b0 = *(const short8*)(bh + k0);
      short8 c0 = *(const short8*)(bl + k0);
      acc = __builtin_amdgcn_mfma_f32_16x16x32_bf16(aH, b0, acc, 0, 0, 0);
      acc = __builtin_amdgcn_mfma_f32_16x16x32_bf16(aL, b0, acc, 0, 0, 0);
      acc = __builtin_amdgcn_mfma_f32_16x16x32_bf16(aH, c0, acc, 0, 0, 0);
    }
    // C layout: batch = w*16 + fq*4 + r, j-row = fm  -> ghG[j'][b]
    const int mb = w * 16 + fq * 4;
    *(f32x4*)(ghG + (size_t)(j0 + fm) * 64 + mb) = acc;
  }
}

// ---------------- per-step kernel B: softmax + gates --------------------------
// grid 512 = (jc 0..63) x (bc 0..7), 512 threads.
// Concurrent prologue: tid<384 stage ghs; tid>=384 (128 thr, waves 6-7) do
// softmax from global fp32 scores + compaction for 8 batches. One barrier.
// Then 4-way-split compacted gather (quarter q = tid>>7), LDS combine.

__global__ __launch_bounds__(512) void gate_kernel(
    const float* __restrict__ scoresG, const int* __restrict__ lens,
    const float* __restrict__ ghG, const float* __restrict__ ctxWc,
    const __hip_bfloat16* __restrict__ gxe, const float* __restrict__ bhhp,
    float* __restrict__ hf, short* __restrict__ hhi, short* __restrict__ hlo,
    float* __restrict__ out, int t)
{
  const int jc = blockIdx.x & 63, bc = blockIdx.x >> 6;     // bc 0..7
  const int j0 = jc * 48, b0 = bc * 8;
  __shared__ float ghs[48 * 9];       // [j_local][bb], stride 9 (bank spread)
  __shared__ float wv[8][64];
  __shared__ short lidx[8][64];
  __shared__ int   cnt[8];
  __shared__ float ps0[384], ps1[384], ps2[384];
  const int tid = threadIdx.x;
  if (tid < 384) {
    // ---- stage ghs (runs concurrently with softmax+compaction below) ----
    const int row = tid >> 3, col = tid & 7;
    ghs[row * 9 + col] = ghG[(size_t)(j0 + row) * 64 + b0 + col];
  } else {
    // ---- softmax + compaction for 8 batches (128 threads, waves 6-7) ----
    const int tt = tid - 384;                 // 0..127
    const int bb = tt >> 4, l4 = (tt & 15) * 4;
    const int b = b0 + bb, len = lens[b];
    if ((tt & 15) == 0) cnt[bb] = 0;          // same wave as its 16-lane group
    float sc[4];
#pragma unroll
    for (int k = 0; k < 4; ++k) {
      const int l = l4 + k;
      sc[k] = (l < len) ? scoresG[b * 64 + l] : -1e9f;
    }
    float m = fmaxf(fmaxf(sc[0], sc[1]), fmaxf(sc[2], sc[3]));
#pragma unroll
    for (int off = 8; off > 0; off >>= 1) m = fmaxf(m, __shfl_xor(m, off));
    float e[4];
    float s = 0.f;
#pragma unroll
    for (int k = 0; k < 4; ++k) { e[k] = __expf(sc[k] - m); s += e[k]; }
#pragma unroll
    for (int off = 8; off > 0; off >>= 1) s += __shfl_xor(s, off);
    const float inv = 1.f / s;
#pragma unroll
    for (int k = 0; k < 4; ++k) {
      const int l = l4 + k;
      const float wl = e[k] * inv;
      if (l < len && wl >= 1e-8f) {
        const int pos = atomicAdd(&cnt[bb], 1);
        lidx[bb][pos] = (short)l;
        wv[bb][pos] = wl;
      }
    }
  }
  __syncthreads();

  const int q = tid >> 7, tl = tid & 127;
  const int bb = tl >> 4, jg = tl & 15;
  const int b = b0 + bb;
  const int n = cnt[bb];
  const int ibeg = (q * n) >> 2;
  const int iend = ((q + 1) * n) >> 2;
  float g0 = 0.f, g1 = 0.f, g2 = 0.f;
  const float* base = ctxWc + (size_t)(b * 64) * 3072 + j0 + jg * 3;
  int i = ibeg;
  for (; i + 3 < iend; i += 4) {          // 4 outstanding scattered loads
    const float w0 = wv[bb][i],     w1 = wv[bb][i + 1];
    const float w2 = wv[bb][i + 2], w3 = wv[bb][i + 3];
    const float* p0 = base + (size_t)lidx[bb][i] * 3072;
    const float* p1 = base + (size_t)lidx[bb][i + 1] * 3072;
    const float* p2 = base + (size_t)lidx[bb][i + 2] * 3072;
    const float* p3 = base + (size_t)lidx[bb][i + 3] * 3072;
    const float a0 = __builtin_nontemporal_load(p0);
    const float a1 = __builtin_nontemporal_load(p0 + 1);
    const float a2 = __builtin_nontemporal_load(p0 + 2);
    const float b0v = __builtin_nontemporal_load(p1);
    const float b1v = __builtin_nontemporal_load(p1 + 1);
    const float b2v = __builtin_nontemporal_load(p1 + 2);
    const float c0 = __builtin_nontemporal_load(p2);
    const float c1 = __builtin_nontemporal_load(p2 + 1);
    const float c2 = __builtin_nontemporal_load(p2 + 2);
    const float d0 = __builtin_nontemporal_load(p3);
    const float d1 = __builtin_nontemporal_load(p3 + 1);
    const float d2 = __builtin_nontemporal_load(p3 + 2);
    g0 += (w0 * a0 + w1 * b0v) + (w2 * c0 + w3 * d0);
    g1 += (w0 * a1 + w1 * b1v) + (w2 * c1 + w3 * d1);
    g2 += (w0 * a2 + w1 * b2v) + (w2 * c2 + w3 * d2);
  }
  for (; i < iend; ++i) {
    const float wa = wv[bb][i];
    const float* pa = base + (size_t)lidx[bb][i] * 3072;
    g0 += wa * __builtin_nontemporal_load(pa);
    g1 += wa * __builtin_nontemporal_load(pa + 1);
    g2 += wa * __builtin_nontemporal_load(pa + 2);
  }
  if (q) {
    const int o = (q - 1) * 128 + tl;
    ps0[o] = g0; ps1[o] = g1; ps2[o] = g2;
  }
  __syncthreads();
  if (q == 0) {
    g0 += (ps0[tl] + ps0[128 + tl]) + ps0[256 + tl];
    g1 += (ps1[tl] + ps1[128 + tl]) + ps1[256 + tl];
    g2 += (ps2[tl] + ps2[128 + tl]) + ps2[256 + tl];

    const int jp = j0 + jg * 3;
    const __hip_bfloat16* ge = gxe + (size_t)(b * 64 + t) * 3072 + jp;
    const float gxr = g0 + __bfloat162float(ge[0]);
    const float gxz = g1 + __bfloat162float(ge[1]);
    const float gxn = g2 + __bfloat162float(ge[2]);
    const float ghr = ghs[(jg * 3 + 0) * 9 + bb] + bhhp[jp + 0];
    const float ghz = ghs[(jg * 3 + 1) * 9 + bb] + bhhp[jp + 1];
    const float ghn = ghs[(jg * 3 + 2) * 9 + bb] + bhhp[jp + 2];
    const float rr = 1.f / (1.f + __expf(-(gxr + ghr)));
    const float zz = 1.f / (1.f + __expf(-(gxz + ghz)));
    const float nn = tanhf(gxn + rr * ghn);
    const int u = jc * 16 + jg;
    const float hold = hf[b * 1024 + u];
    const float hn = (1.f - zz) * nn + zz * hold;
    out[(size_t)(b * 64 + t) * 1024 + u] = hn;
    hf[b * 1024 + u] = hn;
    __hip_bfloat16 hh = __float2bfloat16(hn);
    hhi[b * 1024 + u] = *reinterpret_cast<short*>(&hh);
    __hip_bfloat16 hl = __float2bfloat16(hn - __bfloat162float(hh));
    hlo[b * 1024 + u] = *reinterpret_cast<short*>(&hl);
    if (t == 63) out[(size_t)64 * 64 * 1024 + b * 1024 + u] = hn;
  }
}

// ---------------- launcher ----------------

extern "C" void kernel_launch(void* const* d_in, const int* in_sizes, int n_in,
                              void* d_out, int out_size, void* d_ws, size_t ws_size,
                              hipStream_t stream)
{
  const int*   tgt  = (const int*)  d_in[0];
  const float* ctx  = (const float*)d_in[1];
  const float* h0   = (const float*)d_in[2];
  const int*   lens = (const int*)  d_in[3];
  const float* embt = (const float*)d_in[4];
  const float* Wa   = (const float*)d_in[5];
  const float* Wih  = (const float*)d_in[6];
  const float* Whh  = (const float*)d_in[7];
  const float* bih  = (const float*)d_in[8];
  const float* bhh  = (const float*)d_in[9];
  float* out = (float*)d_out;

  char* p = (char*)d_ws;
  auto take = [&](size_t bytes) {
    char* q = p;
    p += (bytes + 255) & ~(size_t)255;
    return q;
  };
  short* ctx_hi = (short*)take((size_t)8388608 * 2);
  short* ctx_lo = (short*)take((size_t)8388608 * 2);
  short* Wa_hi  = (short*)take((size_t)2097152 * 2);
  short* Wa_lo  = (short*)take((size_t)2097152 * 2);
  short* WcH    = (short*)take((size_t)3072 * 2048 * 2);
  short* WcL    = (short*)take((size_t)3072 * 2048 * 2);
  short* We_p   = (short*)take((size_t)3072 * 512 * 2);
  short* WhH    = (short*)take((size_t)3072 * 1024 * 2);
  short* WhL    = (short*)take((size_t)3072 * 1024 * 2);
  float* bih_p  = (float*)take(3072 * 4);
  float* bhh_p  = (float*)take(3072 * 4);
  short* emb_bf = (short*)take((size_t)4096 * 512 * 2);
  float* ctxW   = (float*)take((size_t)4096 * 1024 * 4);
  float* ctxWc  = (float*)take((size_t)4096 * 3072 * 4);
  short* gxe    = (short*)take((size_t)4096 * 3072 * 2);
  float* hf     = (float*)take((size_t)65536 * 4);
  short* hhi    = (short*)take((size_t)65536 * 2);
  short* hlo    = (short*)take((size_t)65536 * 2);
  float* scoresG= (float*)take((size_t)4096 * 4);
  float* ghG    = (float*)take((size_t)3072 * 64 * 4);

  // prologue: conversions
  split_bf16_kernel<<<2048, 256, 0, stream>>>(ctx, (__hip_bfloat16*)ctx_hi,
                                              (__hip_bfloat16*)ctx_lo, 8388608);
  split_bf16_kernel<<<1024, 256, 0, stream>>>(Wa, (__hip_bfloat16*)Wa_hi,
                                              (__hip_bfloat16*)Wa_lo, 2097152);
  prep_weights<<<3072, 256, 0, stream>>>(Wih, Whh, bih, bhh,
      (__hip_bfloat16*)WcH, (__hip_bfloat16*)WcL, (__hip_bfloat16*)We_p,
      (__hip_bfloat16*)WhH, (__hip_bfloat16*)WhL, bih_p, bhh_p);
  emb_gather<<<4096, 256, 0, stream>>>(tgt, embt, (__hip_bfloat16*)emb_bf);
  h0_init<<<256, 256, 0, stream>>>(h0, hf, (__hip_bfloat16*)hhi,
                                   (__hip_bfloat16*)hlo);

  // ctxW = ctx @ Wa^T   (split-bf16 fused 3-product, fp32 out)
  gemm_bt3<<<dim3(8, 32), 256, 0, stream>>>(ctx_hi, ctx_lo, Wa_hi, Wa_lo,
                                            ctxW, 4096, 1024, 2048);
  // ctxWc = ctx @ Wc_perm^T (split-bf16 fused 3-product, fp32 out)
  gemm_bt3<<<dim3(24, 32), 256, 0, stream>>>(ctx_hi, ctx_lo, WcH, WcL,
                                             ctxWc, 4096, 3072, 2048);
  // gxe = emb @ We_perm^T + b_ih (bf16 out; |gxe| ~ 3e-3, rounding negligible)
  gemm_bt<<<dim3(24, 32), 256, 0, stream>>>(emb_bf, We_p, nullptr,
                                            (__hip_bfloat16*)gxe, bih_p,
                                            4096, 3072, 512, FLAG_BF);

  // sequential recurrence: 2 launches per step
  for (int t = 0; t < 64; ++t) {
    step_a<<<448, 256, 0, stream>>>(hf, ctxW, lens, scoresG,
                                    hhi, hlo, WhH, WhL, ghG);
    gate_kernel<<<512, 512, 0, stream>>>(scoresG, lens, ghG, ctxWc,
        (const __hip_bfloat16*)gxe, bhh_p, hf, hhi, hlo, out, t);
  }
}

// Round 11
// 2286.898 us; speedup vs baseline: 1.0218x; 1.0218x over previous
//
#include <hip/hip_runtime.h>
#include <hip/hip_bf16.h>

// DecoderRNNsearch on MI355X — round 12: revert to r10 (best verified,
// 2283.9 us) after r11's score-split/concurrent-prologue regressed +53 us.
// Single safe addition: split_bf16_kernel vectorized to float4/ushort4
// (identical per-element math; G13 — hipcc won't auto-vectorize bf16 streams).
// Structure: swizzled 128x128 GEMMs (bank conflicts measured 0), step_a
// 256 blocks (64 attn+softmax fused, 192x16-row gh), gate 512 blocks x
// 512 thr with 4-way-split compacted gather. All loop numerics fp32 /
// split-bf16 exact.

using short8 = __attribute__((ext_vector_type(8))) short;
using f32x4  = __attribute__((ext_vector_type(4))) float;

#define FLAG_ACC 1
#define FLAG_BF  2

__device__ __forceinline__ void gld16(const void* g, void* l) {
  __builtin_amdgcn_global_load_lds(
      (const __attribute__((address_space(1))) unsigned int*)g,
      (__attribute__((address_space(3))) unsigned int*)l, 16, 0, 0);
}

__device__ __forceinline__ unsigned short f2bf_hi(float v) {
  __hip_bfloat16 h = __float2bfloat16(v);
  return *reinterpret_cast<unsigned short*>(&h);
}

// ---------------- conversion / prep kernels ----------------

__global__ __launch_bounds__(256) void split_bf16_kernel(
    const float* __restrict__ x, __hip_bfloat16* __restrict__ hi,
    __hip_bfloat16* __restrict__ lo, int n)   // n divisible by 4
{
  int i = blockIdx.x * blockDim.x + threadIdx.x;   // float4 index
  const int stride = gridDim.x * blockDim.x;
  const int n4 = n >> 2;
  for (; i < n4; i += stride) {
    const float4 v = ((const float4*)x)[i];
    ushort4 h, l;
    h.x = f2bf_hi(v.x);
    h.y = f2bf_hi(v.y);
    h.z = f2bf_hi(v.z);
    h.w = f2bf_hi(v.w);
    __hip_bfloat16 bx = *reinterpret_cast<__hip_bfloat16*>(&h.x);
    __hip_bfloat16 by = *reinterpret_cast<__hip_bfloat16*>(&h.y);
    __hip_bfloat16 bz = *reinterpret_cast<__hip_bfloat16*>(&h.z);
    __hip_bfloat16 bw = *reinterpret_cast<__hip_bfloat16*>(&h.w);
    l.x = f2bf_hi(v.x - __bfloat162float(bx));
    l.y = f2bf_hi(v.y - __bfloat162float(by));
    l.z = f2bf_hi(v.z - __bfloat162float(bz));
    l.w = f2bf_hi(v.w - __bfloat162float(bw));
    ((ushort4*)hi)[i] = h;
    ((ushort4*)lo)[i] = l;
  }
}

// permute rows j' = 3u+g  <-  source row g*1024+u ; split to bf16 hi/lo
__global__ __launch_bounds__(256) void prep_weights(
    const float* __restrict__ Wih, const float* __restrict__ Whh,
    const float* __restrict__ bih, const float* __restrict__ bhh,
    __hip_bfloat16* __restrict__ WcH, __hip_bfloat16* __restrict__ WcL,
    __hip_bfloat16* __restrict__ We,
    __hip_bfloat16* __restrict__ WhH, __hip_bfloat16* __restrict__ WhL,
    float* __restrict__ bihp, float* __restrict__ bhhp)
{
  const int jp = blockIdx.x;           // 0..3071
  const int u = jp / 3, g = jp - 3 * u;
  const int src = g * 1024 + u;
  for (int c = threadIdx.x; c < 2048; c += 256) {
    float v = Wih[(size_t)src * 2560 + 512 + c];
    __hip_bfloat16 h = __float2bfloat16(v);
    WcH[(size_t)jp * 2048 + c] = h;
    WcL[(size_t)jp * 2048 + c] = __float2bfloat16(v - __bfloat162float(h));
  }
  for (int c = threadIdx.x; c < 512; c += 256)
    We[(size_t)jp * 512 + c] = __float2bfloat16(Wih[(size_t)src * 2560 + c]);
  for (int c = threadIdx.x; c < 1024; c += 256) {
    float v = Whh[(size_t)src * 1024 + c];
    __hip_bfloat16 h = __float2bfloat16(v);
    WhH[(size_t)jp * 1024 + c] = h;
    WhL[(size_t)jp * 1024 + c] = __float2bfloat16(v - __bfloat162float(h));
  }
  if (threadIdx.x == 0) { bihp[jp] = bih[src]; bhhp[jp] = bhh[src]; }
}

__global__ __launch_bounds__(256) void emb_gather(
    const int* __restrict__ tgt, const float* __restrict__ table,
    __hip_bfloat16* __restrict__ outb)
{
  const int row = blockIdx.x;          // b*64+t, 0..4095
  const int v = tgt[row];
  for (int c = threadIdx.x; c < 512; c += 256)
    outb[(size_t)row * 512 + c] = __float2bfloat16(table[(size_t)v * 512 + c]);
}

__global__ __launch_bounds__(256) void h0_init(
    const float* __restrict__ h0, float* __restrict__ hf,
    __hip_bfloat16* __restrict__ hhi, __hip_bfloat16* __restrict__ hlo)
{
  const int i = blockIdx.x * 256 + threadIdx.x;   // grid 256 -> 65536
  float v = h0[i];
  hf[i] = v;
  __hip_bfloat16 h = __float2bfloat16(v);
  hhi[i] = h;
  hlo[i] = __float2bfloat16(v - __bfloat162float(h));
}

// ---------------- bf16 GEMM  C[M,N] = A[M,K] @ B[N,K]^T (single pass) -------
// 128x128 tile, 4 waves, BK=32, global_load_lds staging, XOR-swizzled LDS
// (pre-swizzled global source + swizzled ds_read; conflicts measured 0).

__global__ __launch_bounds__(256) void gemm_bt(
    const short* __restrict__ A, const short* __restrict__ B,
    float* __restrict__ Cf, __hip_bfloat16* __restrict__ Cb,
    const float* __restrict__ bias, int M, int N, int K, int flags)
{
  __shared__ __align__(16) short As[128 * 32];
  __shared__ __align__(16) short Bs[128 * 32];
  const int tid = threadIdx.x, lane = tid & 63, w = tid >> 6;
  const int m0 = blockIdx.y * 128, n0 = blockIdx.x * 128;
  const int wm = (w >> 1) * 64, wn = (w & 1) * 64;
  const int srow = lane >> 2;
  const int scol = (((lane & 3) ^ ((lane >> 3) & 3)) * 8);   // pre-swizzled src
  f32x4 zero = {0.f, 0.f, 0.f, 0.f};
  f32x4 acc[4][4];
#pragma unroll
  for (int i = 0; i < 4; ++i)
#pragma unroll
    for (int j = 0; j < 4; ++j) acc[i][j] = zero;

  for (int k0 = 0; k0 < K; k0 += 32) {
    __syncthreads();
#pragma unroll
    for (int s = 0; s < 2; ++s) {
      const int chunk = w * 2 + s;
      const int r = chunk * 16 + srow;
      gld16(A + (size_t)(m0 + r) * K + k0 + scol, As + chunk * 512);
      gld16(B + (size_t)(n0 + r) * K + k0 + scol, Bs + chunk * 512);
    }
    __syncthreads();
    const int fm = lane & 15, fq = lane >> 4;
    const int cbs = (fq ^ ((fm >> 1) & 3)) * 8;              // swizzled read
    short8 af[4], bq[4];
#pragma unroll
    for (int i = 0; i < 4; ++i)
      af[i] = *(const short8*)(As + (wm + i * 16 + fm) * 32 + cbs);
#pragma unroll
    for (int j = 0; j < 4; ++j)
      bq[j] = *(const short8*)(Bs + (wn + j * 16 + fm) * 32 + cbs);
#pragma unroll
    for (int i = 0; i < 4; ++i)
#pragma unroll
      for (int j = 0; j < 4; ++j)
        acc[i][j] = __builtin_amdgcn_mfma_f32_16x16x32_bf16(af[i], bq[j], acc[i][j], 0, 0, 0);
  }

  const int cn = lane & 15, cq = (lane >> 4) * 4;
#pragma unroll
  for (int i = 0; i < 4; ++i)
#pragma unroll
    for (int j = 0; j < 4; ++j)
#pragma unroll
      for (int r = 0; r < 4; ++r) {
        const int m = m0 + wm + i * 16 + cq + r;
        const int n = n0 + wn + j * 16 + cn;
        float v = acc[i][j][r];
        if (flags & FLAG_ACC) v += Cf[(size_t)m * N + n];
        if (bias) v += bias[n];
        if (flags & FLAG_BF) Cb[(size_t)m * N + n] = __float2bfloat16(v);
        else                 Cf[(size_t)m * N + n] = v;
      }
}

// ---------------- fused split-bf16 triple GEMM --------------------------------
// C = AH@BH^T + AL@BH^T + AH@BL^T  (effective-fp32 product), one staging pass.
// Same XOR-swizzled LDS layout as gemm_bt.

__global__ __launch_bounds__(256) void gemm_bt3(
    const short* __restrict__ AH, const short* __restrict__ AL,
    const short* __restrict__ BH, const short* __restrict__ BL,
    float* __restrict__ Cf, int M, int N, int K)
{
  __shared__ __align__(16) short AsH[128 * 32];
  __shared__ __align__(16) short AsL[128 * 32];
  __shared__ __align__(16) short BsH[128 * 32];
  __shared__ __align__(16) short BsL[128 * 32];
  const int tid = threadIdx.x, lane = tid & 63, w = tid >> 6;
  const int m0 = blockIdx.y * 128, n0 = blockIdx.x * 128;
  const int wm = (w >> 1) * 64, wn = (w & 1) * 64;
  const int srow = lane >> 2;
  const int scol = (((lane & 3) ^ ((lane >> 3) & 3)) * 8);   // pre-swizzled src
  f32x4 zero = {0.f, 0.f, 0.f, 0.f};
  f32x4 acc[4][4];
#pragma unroll
  for (int i = 0; i < 4; ++i)
#pragma unroll
    for (int j = 0; j < 4; ++j) acc[i][j] = zero;

  for (int k0 = 0; k0 < K; k0 += 32) {
    __syncthreads();
#pragma unroll
    for (int s = 0; s < 2; ++s) {
      const int chunk = w * 2 + s;
      const int r = chunk * 16 + srow;
      const size_t ao = (size_t)(m0 + r) * K + k0 + scol;
      const size_t bo = (size_t)(n0 + r) * K + k0 + scol;
      gld16(AH + ao, AsH + chunk * 512);
      gld16(AL + ao, AsL + chunk * 512);
      gld16(BH + bo, BsH + chunk * 512);
      gld16(BL + bo, BsL + chunk * 512);
    }
    __syncthreads();
    const int fm = lane & 15, fq = lane >> 4;
    const int cbs = (fq ^ ((fm >> 1) & 3)) * 8;              // swizzled read
    short8 ah[4], al[4], bh[4], bl[4];
#pragma unroll
    for (int i = 0; i < 4; ++i) {
      const int off = (wm + i * 16 + fm) * 32 + cbs;
      ah[i] = *(const short8*)(AsH + off);
      al[i] = *(const short8*)(AsL + off);
    }
#pragma unroll
    for (int j = 0; j < 4; ++j) {
      const int off = (wn + j * 16 + fm) * 32 + cbs;
      bh[j] = *(const short8*)(BsH + off);
      bl[j] = *(const short8*)(BsL + off);
    }
#pragma unroll
    for (int i = 0; i < 4; ++i)
#pragma unroll
      for (int j = 0; j < 4; ++j) {
        acc[i][j] = __builtin_amdgcn_mfma_f32_16x16x32_bf16(ah[i], bh[j], acc[i][j], 0, 0, 0);
        acc[i][j] = __builtin_amdgcn_mfma_f32_16x16x32_bf16(al[i], bh[j], acc[i][j], 0, 0, 0);
        acc[i][j] = __builtin_amdgcn_mfma_f32_16x16x32_bf16(ah[i], bl[j], acc[i][j], 0, 0, 0);
      }
  }

  const int cn = lane & 15, cq = (lane >> 4) * 4;
#pragma unroll
  for (int i = 0; i < 4; ++i)
#pragma unroll
    for (int j = 0; j < 4; ++j)
#pragma unroll
      for (int r = 0; r < 4; ++r) {
        const int m = m0 + wm + i * 16 + cq + r;
        const int n = n0 + wn + j * 16 + cn;
        Cf[(size_t)m * N + n] = acc[i][j][r];
      }
}

// ---------------- per-step kernel A: attn (blk 0-63) + gh (blk 64-255) -------

__global__ __launch_bounds__(256) void step_a(
    const float* __restrict__ hf, const float* __restrict__ ctxW,
    const int* __restrict__ lens, float* __restrict__ attn,
    const short* __restrict__ hhi, const short* __restrict__ hlo,
    const short* __restrict__ WhH, const short* __restrict__ WhL,
    float* __restrict__ ghG)
{
  const int tid = threadIdx.x;
  if (blockIdx.x < 64) {
    // ---- attention scores + masked softmax for batch b (verified r4) ----
    __shared__ float hs[1024];
    __shared__ float part[256];
    const int b = blockIdx.x;
    const int len = lens[b];
    ((float4*)hs)[tid] = ((const float4*)(hf + b * 1024))[tid];
    __syncthreads();
    const int l = tid >> 2, q = tid & 3;
    float sx = 0.f, sy = 0.f, sz = 0.f, sw = 0.f;
    if (l < len) {
      const float4* row = (const float4*)(ctxW + ((size_t)(b * 64 + l)) * 1024 + q * 256);
      const float4* hh = (const float4*)(hs + q * 256);
#pragma unroll 8
      for (int i = 0; i < 64; ++i) {
        float4 a = row[i], c = hh[i];
        sx += a.x * c.x; sy += a.y * c.y; sz += a.z * c.z; sw += a.w * c.w;
      }
    }
    part[tid] = (sx + sy) + (sz + sw);
    __syncthreads();
    if (tid < 64) {   // exactly wave 0; tid == context position
      float sc = part[tid * 4] + part[tid * 4 + 1] + part[tid * 4 + 2] + part[tid * 4 + 3];
      if (tid >= len) sc = -1e9f;
      float m = sc;
#pragma unroll
      for (int off = 32; off > 0; off >>= 1) m = fmaxf(m, __shfl_xor(m, off));
      float e = __expf(sc - m);
      float sum = e;
#pragma unroll
      for (int off = 32; off > 0; off >>= 1) sum += __shfl_xor(sum, off);
      attn[b * 64 + tid] = e / sum;
    }
  } else {
    // ---- gh = Whh_slice @ h, 16 rows/block (verified r5/r10) ----
    const int j0 = (blockIdx.x - 64) * 16;
    const int lane = tid & 63, w = tid >> 6;
    const int fm = lane & 15, fq = lane >> 4;
    f32x4 acc = {0.f, 0.f, 0.f, 0.f};
    const short* ah = hhi + (w * 16 + fm) * 1024 + fq * 8;   // batches w*16..+15
    const short* al = hlo + (w * 16 + fm) * 1024 + fq * 8;
    const short* bh = WhH + (size_t)(j0 + fm) * 1024 + fq * 8;
    const short* bl = WhL + (size_t)(j0 + fm) * 1024 + fq * 8;
#pragma unroll 4
    for (int k0 = 0; k0 < 1024; k0 += 32) {
      short8 aH = *(const short8*)(ah + k0);
      short8 aL = *(const short8*)(al + k0);
      short8 b0 = *(const short8*)(bh + k0);
      short8 c0 = *(const short8*)(bl + k0);
      acc = __builtin_amdgcn_mfma_f32_16x16x32_bf16(aH, b0, acc, 0, 0, 0);
      acc = __builtin_amdgcn_mfma_f32_16x16x32_bf16(aL, b0, acc, 0, 0, 0);
      acc = __builtin_amdgcn_mfma_f32_16x16x32_bf16(aH, c0, acc, 0, 0, 0);
    }
    // C layout: batch = w*16 + fq*4 + r, j-row = fm  -> ghG[j'][b]
    const int mb = w * 16 + fq * 4;
    *(f32x4*)(ghG + (size_t)(j0 + fm) * 64 + mb) = acc;
  }
}

// ---------------- per-step kernel B: gates ------------------------------------
// grid 512 = (jc 0..63) x (bc 0..7), 512 threads. Block: 16 units (48 j') x
// 8 batches. Compacted l-list split across 4 thread-quarters (LDS combine):
// quarter q = tid>>7 owns [q*n/4, (q+1)*n/4). fp32 ctxWc, nontemporal loads.

__global__ __launch_bounds__(512) void gate_kernel(
    const float* __restrict__ attn, const int* __restrict__ lens,
    const float* __restrict__ ghG, const float* __restrict__ ctxWc,
    const __hip_bfloat16* __restrict__ gxe, const float* __restrict__ bhhp,
    float* __restrict__ hf, short* __restrict__ hhi, short* __restrict__ hlo,
    float* __restrict__ out, int t)
{
  const int jc = blockIdx.x & 63, bc = blockIdx.x >> 6;     // bc 0..7
  const int j0 = jc * 48, b0 = bc * 8;
  __shared__ float ghs[48 * 9];       // [j_local][bb], stride 9 (bank spread)
  __shared__ float wv[8][64];
  __shared__ short lidx[8][64];
  __shared__ int   cnt[8];
  __shared__ float ps0[384], ps1[384], ps2[384];
  const int tid = threadIdx.x;
  if (tid < 8) cnt[tid] = 0;
  if (tid < 384) {
    const int row = tid >> 3, col = tid & 7;
    ghs[row * 9 + col] = ghG[(size_t)(j0 + row) * 64 + b0 + col];
  }
  __syncthreads();
  if (tid < 128) {
    const int bb = tid >> 4, l4 = (tid & 15) * 4;
    const int b = b0 + bb, len = lens[b];
#pragma unroll
    for (int k = 0; k < 4; ++k) {
      const int l = l4 + k;
      const float wl = attn[b * 64 + l];
      if (l < len && wl >= 1e-8f) {
        const int pos = atomicAdd(&cnt[bb], 1);
        lidx[bb][pos] = (short)l;
        wv[bb][pos] = wl;
      }
    }
  }
  __syncthreads();

  const int q = tid >> 7, tl = tid & 127;
  const int bb = tl >> 4, jg = tl & 15;
  const int b = b0 + bb;
  const int n = cnt[bb];
  const int ibeg = (q * n) >> 2;
  const int iend = ((q + 1) * n) >> 2;
  float g0 = 0.f, g1 = 0.f, g2 = 0.f;
  const float* base = ctxWc + (size_t)(b * 64) * 3072 + j0 + jg * 3;
  int i = ibeg;
  for (; i + 3 < iend; i += 4) {          // 4 outstanding scattered loads
    const float w0 = wv[bb][i],     w1 = wv[bb][i + 1];
    const float w2 = wv[bb][i + 2], w3 = wv[bb][i + 3];
    const float* p0 = base + (size_t)lidx[bb][i] * 3072;
    const float* p1 = base + (size_t)lidx[bb][i + 1] * 3072;
    const float* p2 = base + (size_t)lidx[bb][i + 2] * 3072;
    const float* p3 = base + (size_t)lidx[bb][i + 3] * 3072;
    const float a0 = __builtin_nontemporal_load(p0);
    const float a1 = __builtin_nontemporal_load(p0 + 1);
    const float a2 = __builtin_nontemporal_load(p0 + 2);
    const float b0v = __builtin_nontemporal_load(p1);
    const float b1v = __builtin_nontemporal_load(p1 + 1);
    const float b2v = __builtin_nontemporal_load(p1 + 2);
    const float c0 = __builtin_nontemporal_load(p2);
    const float c1 = __builtin_nontemporal_load(p2 + 1);
    const float c2 = __builtin_nontemporal_load(p2 + 2);
    const float d0 = __builtin_nontemporal_load(p3);
    const float d1 = __builtin_nontemporal_load(p3 + 1);
    const float d2 = __builtin_nontemporal_load(p3 + 2);
    g0 += (w0 * a0 + w1 * b0v) + (w2 * c0 + w3 * d0);
    g1 += (w0 * a1 + w1 * b1v) + (w2 * c1 + w3 * d1);
    g2 += (w0 * a2 + w1 * b2v) + (w2 * c2 + w3 * d2);
  }
  for (; i < iend; ++i) {
    const float wa = wv[bb][i];
    const float* pa = base + (size_t)lidx[bb][i] * 3072;
    g0 += wa * __builtin_nontemporal_load(pa);
    g1 += wa * __builtin_nontemporal_load(pa + 1);
    g2 += wa * __builtin_nontemporal_load(pa + 2);
  }
  if (q) {
    const int o = (q - 1) * 128 + tl;
    ps0[o] = g0; ps1[o] = g1; ps2[o] = g2;
  }
  __syncthreads();
  if (q == 0) {
    g0 += (ps0[tl] + ps0[128 + tl]) + ps0[256 + tl];
    g1 += (ps1[tl] + ps1[128 + tl]) + ps1[256 + tl];
    g2 += (ps2[tl] + ps2[128 + tl]) + ps2[256 + tl];

    const int jp = j0 + jg * 3;
    const __hip_bfloat16* ge = gxe + (size_t)(b * 64 + t) * 3072 + jp;
    const float gxr = g0 + __bfloat162float(ge[0]);
    const float gxz = g1 + __bfloat162float(ge[1]);
    const float gxn = g2 + __bfloat162float(ge[2]);
    const float ghr = ghs[(jg * 3 + 0) * 9 + bb] + bhhp[jp + 0];
    const float ghz = ghs[(jg * 3 + 1) * 9 + bb] + bhhp[jp + 1];
    const float ghn = ghs[(jg * 3 + 2) * 9 + bb] + bhhp[jp + 2];
    const float rr = 1.f / (1.f + __expf(-(gxr + ghr)));
    const float zz = 1.f / (1.f + __expf(-(gxz + ghz)));
    const float nn = tanhf(gxn + rr * ghn);
    const int u = jc * 16 + jg;
    const float hold = hf[b * 1024 + u];
    const float hn = (1.f - zz) * nn + zz * hold;
    out[(size_t)(b * 64 + t) * 1024 + u] = hn;
    hf[b * 1024 + u] = hn;
    __hip_bfloat16 hh = __float2bfloat16(hn);
    hhi[b * 1024 + u] = *reinterpret_cast<short*>(&hh);
    __hip_bfloat16 hl = __float2bfloat16(hn - __bfloat162float(hh));
    hlo[b * 1024 + u] = *reinterpret_cast<short*>(&hl);
    if (t == 63) out[(size_t)64 * 64 * 1024 + b * 1024 + u] = hn;
  }
}

// ---------------- launcher ----------------

extern "C" void kernel_launch(void* const* d_in, const int* in_sizes, int n_in,
                              void* d_out, int out_size, void* d_ws, size_t ws_size,
                              hipStream_t stream)
{
  const int*   tgt  = (const int*)  d_in[0];
  const float* ctx  = (const float*)d_in[1];
  const float* h0   = (const float*)d_in[2];
  const int*   lens = (const int*)  d_in[3];
  const float* embt = (const float*)d_in[4];
  const float* Wa   = (const float*)d_in[5];
  const float* Wih  = (const float*)d_in[6];
  const float* Whh  = (const float*)d_in[7];
  const float* bih  = (const float*)d_in[8];
  const float* bhh  = (const float*)d_in[9];
  float* out = (float*)d_out;

  char* p = (char*)d_ws;
  auto take = [&](size_t bytes) {
    char* q = p;
    p += (bytes + 255) & ~(size_t)255;
    return q;
  };
  short* ctx_hi = (short*)take((size_t)8388608 * 2);
  short* ctx_lo = (short*)take((size_t)8388608 * 2);
  short* Wa_hi  = (short*)take((size_t)2097152 * 2);
  short* Wa_lo  = (short*)take((size_t)2097152 * 2);
  short* WcH    = (short*)take((size_t)3072 * 2048 * 2);
  short* WcL    = (short*)take((size_t)3072 * 2048 * 2);
  short* We_p   = (short*)take((size_t)3072 * 512 * 2);
  short* WhH    = (short*)take((size_t)3072 * 1024 * 2);
  short* WhL    = (short*)take((size_t)3072 * 1024 * 2);
  float* bih_p  = (float*)take(3072 * 4);
  float* bhh_p  = (float*)take(3072 * 4);
  short* emb_bf = (short*)take((size_t)4096 * 512 * 2);
  float* ctxW   = (float*)take((size_t)4096 * 1024 * 4);
  float* ctxWc  = (float*)take((size_t)4096 * 3072 * 4);
  short* gxe    = (short*)take((size_t)4096 * 3072 * 2);
  float* hf     = (float*)take((size_t)65536 * 4);
  short* hhi    = (short*)take((size_t)65536 * 2);
  short* hlo    = (short*)take((size_t)65536 * 2);
  float* attn   = (float*)take((size_t)4096 * 4);
  float* ghG    = (float*)take((size_t)3072 * 64 * 4);

  // prologue: conversions (float4-vectorized splits)
  split_bf16_kernel<<<2048, 256, 0, stream>>>(ctx, (__hip_bfloat16*)ctx_hi,
                                              (__hip_bfloat16*)ctx_lo, 8388608);
  split_bf16_kernel<<<1024, 256, 0, stream>>>(Wa, (__hip_bfloat16*)Wa_hi,
                                              (__hip_bfloat16*)Wa_lo, 2097152);
  prep_weights<<<3072, 256, 0, stream>>>(Wih, Whh, bih, bhh,
      (__hip_bfloat16*)WcH, (__hip_bfloat16*)WcL, (__hip_bfloat16*)We_p,
      (__hip_bfloat16*)WhH, (__hip_bfloat16*)WhL, bih_p, bhh_p);
  emb_gather<<<4096, 256, 0, stream>>>(tgt, embt, (__hip_bfloat16*)emb_bf);
  h0_init<<<256, 256, 0, stream>>>(h0, hf, (__hip_bfloat16*)hhi,
                                   (__hip_bfloat16*)hlo);

  // ctxW = ctx @ Wa^T   (split-bf16 fused 3-product, fp32 out)
  gemm_bt3<<<dim3(8, 32), 256, 0, stream>>>(ctx_hi, ctx_lo, Wa_hi, Wa_lo,
                                            ctxW, 4096, 1024, 2048);
  // ctxWc = ctx @ Wc_perm^T (split-bf16 fused 3-product, fp32 out)
  gemm_bt3<<<dim3(24, 32), 256, 0, stream>>>(ctx_hi, ctx_lo, WcH, WcL,
                                             ctxWc, 4096, 3072, 2048);
  // gxe = emb @ We_perm^T + b_ih (bf16 out; |gxe| ~ 3e-3, rounding negligible)
  gemm_bt<<<dim3(24, 32), 256, 0, stream>>>(emb_bf, We_p, nullptr,
                                            (__hip_bfloat16*)gxe, bih_p,
                                            4096, 3072, 512, FLAG_BF);

  // sequential recurrence: 2 launches per step
  for (int t = 0; t < 64; ++t) {
    step_a<<<256, 256, 0, stream>>>(hf, ctxW, lens, attn,
                                    hhi, hlo, WhH, WhL, ghG);
    gate_kernel<<<512, 512, 0, stream>>>(attn, lens, ghG, ctxWc,
        (const __hip_bfloat16*)gxe, bhh_p, hf, hhi, hlo, out, t);
  }
}